// Round 8
// baseline (296.015 us; speedup 1.0000x reference)
//
#include <hip/hip_runtime.h>
#include <hip/hip_fp16.h>
#include <math.h>

#define D_ 128
#define K_ 1024
#define N_ 65536
#define DECAY_ 0.99f
#define OMD_ 0.01f
#define EPS_ 1e-5f
#define VQC_ 0.25f
#define SSPLIT 4
#define MARGIN_ 0.1f
#define GATHER_BLOCKS 2048

typedef __attribute__((ext_vector_type(8))) _Float16 half8;
typedef __attribute__((ext_vector_type(4))) float f32x4;

// ---- workspace offsets (in 4-byte elements) ----
#define WOFF_CODE  0          // int[65536]
#define WOFF_E2    65536      // float[1024]
#define WOFF_CNT   66560      // int[1024]
#define WOFF_SSQ   67584      // float[1]
#define WOFF_RCNT  67585      // int[1]    (CNT..RCNT zeroed by k_transpose block 0)
#define WOFF_BASE  67648      // int[1025]
#define WOFF_CURS  68736      // int[1024]
#define WOFF_ORDER 69760      // int[65536]
#define WOFF_CS    135296     // float[1024] (unused)
#define WOFF_ET    136320     // float[131072] (K x D), 16B aligned
#define WOFF_PART  267392     // float[SSPLIT * 131072]
#define WOFF_RLIST 791680     // int[65536]; reused as float ssq_part[GATHER_BLOCKS] after k_fix
#define WOFF_EF    857216     // ushort[131072] frag-ordered fp16 of -2E
// total ~923K elements (~3.7 MB)

// ---- output offsets (in floats), reference return order ----
#define OOFF_Q     0          // [16,4096,128]
#define OOFF_DIFF  8388608    // scalar
#define OOFF_CODE  8388609    // [16,4096]
#define OOFF_NEMB  8454145    // [128,1024]
#define OOFF_NCS   8585217    // [1024]
#define OOFF_NMEAN 8586241    // [128,1024]

// -------------------------------------------------------------------
// E [D][K] -> Et [K][D]; block (0,0) also zeroes cnt[1024]+ssq+rcnt
__global__ void k_transpose(const float* __restrict__ E, float* __restrict__ Et,
                            int* __restrict__ cnt) {
    __shared__ float tile[32][33];
    int k0 = blockIdx.x * 32;
    int d0 = blockIdx.y * 32;
    int tx = threadIdx.x;            // 0..31
    if (blockIdx.x == 0 && blockIdx.y == 0) {
        int t = threadIdx.y * 32 + tx;             // 0..255
        for (int i = t; i < 1026; i += 256) cnt[i] = 0;   // cnt[1024], ssq, rcnt
    }
    for (int ty = threadIdx.y; ty < 32; ty += 8)
        tile[ty][tx] = E[(d0 + ty) * K_ + (k0 + tx)];
    __syncthreads();
    for (int ty = threadIdx.y; ty < 32; ty += 8)
        Et[(k0 + ty) * D_ + (d0 + tx)] = tile[tx][ty];
}

// -------------------------------------------------------------------
// Build fragment-ordered fp16 plane of g = -2*E, and e2[k] = sum E^2.
// Layout: index T = ((g16*4 + s)*64 + L); lane L holds code g16*16+(L&15),
// dims s*32 + (L>>4)*8 .. +8  => B-operand frag for mfma 16x16x32.
__global__ void k_prep_ef(const float* __restrict__ Et, unsigned short* __restrict__ Ef,
                          float* __restrict__ e2) {
    __shared__ float e2s[16];
    int tid = threadIdx.x;
    int b = blockIdx.x;                        // 0..63
    int T = b * 256 + tid;
    int L = tid & 63;
    int code = b * 16 + (L & 15);
    int d0 = ((tid >> 6) & 3) * 32 + ((L >> 4) << 3);
    if (tid < 16) e2s[tid] = 0.f;
    __syncthreads();
    const float* src = Et + code * D_ + d0;
    unsigned short h[8];
    float sq = 0.f;
    #pragma unroll
    for (int j = 0; j < 8; ++j) {
        float e = src[j];
        sq = fmaf(e, e, sq);
        h[j] = __half_as_ushort(__float2half(-2.f * e));
    }
    #pragma unroll
    for (int j = 0; j < 8; ++j) Ef[T * 8 + j] = h[j];
    atomicAdd(&e2s[L & 15], sq);
    __syncthreads();
    if (tid < 16) e2[b * 16 + tid] = e2s[tid];
}

// -------------------------------------------------------------------
// MFMA argmin: dist = e2[k] + x.(-2e), fp16 inputs / fp32 accumulate.
// Block = 64 tokens, 4 waves. Wave (mg,ng): m-tiles 2mg..2mg+1 (32 tokens),
// n-half ng (32 of 64 staged codes) => 16 MACs per LDS frag byte.
// fp16 dist-error sigma ~9e-3; exact top-2 guard at MARGIN_ -> k_fix.
__launch_bounds__(256, 4)
__global__ void k_argmin_mfma(const float* __restrict__ x, const unsigned short* __restrict__ Ef,
                              const float* __restrict__ e2,
                              int* __restrict__ code_i, float* __restrict__ code_f,
                              int* __restrict__ cnt, int* __restrict__ rcnt,
                              int* __restrict__ rlist) {
    __shared__ unsigned short Bs[8192];   // 16 KB, one 64-code chunk (fp16)
    __shared__ float e2s[K_];
    int tid = threadIdx.x;
    int w = tid >> 6, L = tid & 63, quad = L >> 4, col = L & 15;
    int mg = w >> 1, ng = w & 1;
    int n0 = blockIdx.x * 64;

    for (int i = tid; i < K_; i += 256) e2s[i] = e2[i];

    // ---- A fragments: 32 tokens/wave (2 m-tiles), fp16 in registers ----
    half8 ah[2][4];
    #pragma unroll
    for (int mt = 0; mt < 2; ++mt) {
        int tok = n0 + (2 * mg + mt) * 16 + col;
        #pragma unroll
        for (int s = 0; s < 4; ++s) {
            const float* p = x + (size_t)tok * D_ + s * 32 + quad * 8;
            float4 u0 = *(const float4*)(p);
            float4 u1 = *(const float4*)(p + 4);
            ah[mt][s][0] = (_Float16)u0.x; ah[mt][s][1] = (_Float16)u0.y;
            ah[mt][s][2] = (_Float16)u0.z; ah[mt][s][3] = (_Float16)u0.w;
            ah[mt][s][4] = (_Float16)u1.x; ah[mt][s][5] = (_Float16)u1.y;
            ah[mt][s][6] = (_Float16)u1.z; ah[mt][s][7] = (_Float16)u1.w;
        }
    }

    float b1[2][4], b2[2][4];
    int   bi[2][4];
    #pragma unroll
    for (int mt = 0; mt < 2; ++mt)
        #pragma unroll
        for (int r = 0; r < 4; ++r) { b1[mt][r] = INFINITY; b2[mt][r] = INFINITY; bi[mt][r] = 0; }

    for (int q = 0; q < 16; ++q) {
        __syncthreads();
        // ---- stage 64-code chunk: flat 16 KB copy ----
        const float4* gh = (const float4*)(Ef + q * 8192);
        #pragma unroll
        for (int i = 0; i < 4; ++i)
            ((float4*)Bs)[i * 256 + tid] = gh[i * 256 + tid];
        __syncthreads();

        // ---- acc init = e2 of this lane's column (this wave's code half) ----
        f32x4 acc[2][2];   // [m-tile][n-sub]
        #pragma unroll
        for (int nn = 0; nn < 2; ++nn) {
            float ev = e2s[q * 64 + (2 * ng + nn) * 16 + col];
            acc[0][nn] = (f32x4){ev, ev, ev, ev};
            acc[1][nn] = (f32x4){ev, ev, ev, ev};
        }

        // ---- 16 MFMA: 4 k-steps x 2 n-subs x 2 m-tiles ----
        #pragma unroll
        for (int s = 0; s < 4; ++s) {
            half8 bh[2];
            #pragma unroll
            for (int nn = 0; nn < 2; ++nn) {
                int off = (((2 * ng + nn) * 4 + s) * 64 + L) * 8;
                bh[nn] = *(const half8*)(Bs + off);
            }
            #pragma unroll
            for (int nn = 0; nn < 2; ++nn) {
                #pragma unroll
                for (int mt = 0; mt < 2; ++mt)
                    acc[mt][nn] = __builtin_amdgcn_mfma_f32_16x16x32_f16(ah[mt][s], bh[nn], acc[mt][nn], 0, 0, 0);
            }
        }

        // ---- fold into running top-2 (ascending code idx => first-min) ----
        #pragma unroll
        for (int nn = 0; nn < 2; ++nn) {
            int ci = q * 64 + (2 * ng + nn) * 16 + col;
            #pragma unroll
            for (int mt = 0; mt < 2; ++mt) {
                #pragma unroll
                for (int r = 0; r < 4; ++r) {
                    float d = acc[mt][nn][r];
                    if (d < b1[mt][r]) {
                        b2[mt][r] = b1[mt][r];
                        b1[mt][r] = d;
                        bi[mt][r] = ci;
                    } else {
                        b2[mt][r] = fminf(b2[mt][r], d);
                    }
                }
            }
        }
    }

    // ---- cross-lane merge over 16 cols, then cross-half merge via LDS ----
    __syncthreads();                        // Bs dead; overlay merge arrays
    float* md1 = (float*)Bs;                // [64 tokens][2 halves]
    float* md2 = md1 + 128;
    int*   mi1 = (int*)(md2 + 128);

    #pragma unroll
    for (int mt = 0; mt < 2; ++mt) {
        #pragma unroll
        for (int r = 0; r < 4; ++r) {
            float bd = b1[mt][r];
            float s2 = b2[mt][r];
            int   ii = bi[mt][r];
            #pragma unroll
            for (int m = 1; m < 16; m <<= 1) {
                float ob  = __shfl_xor(bd, m);
                int   oi  = __shfl_xor(ii, m);
                float os2 = __shfl_xor(s2, m);
                float hi  = fmaxf(bd, ob);
                s2 = fminf(hi, fminf(s2, os2));   // exact combined second-best
                if (ob < bd || (ob == bd && oi < ii)) { bd = ob; ii = oi; }
            }
            if (col == 0) {
                int tl = (2 * mg + mt) * 16 + quad * 4 + r;
                md1[tl * 2 + ng] = bd;
                md2[tl * 2 + ng] = s2;
                mi1[tl * 2 + ng] = ii;
            }
        }
    }
    __syncthreads();
    if (tid < 64) {
        float d1a = md1[tid * 2], d1b = md1[tid * 2 + 1];
        float d2a = md2[tid * 2], d2b = md2[tid * 2 + 1];
        int   ia  = mi1[tid * 2], ib  = mi1[tid * 2 + 1];
        float bd; int ii;
        if (d1b < d1a || (d1b == d1a && ib < ia)) { bd = d1b; ii = ib; }
        else                                      { bd = d1a; ii = ia; }
        float s2 = fminf(fmaxf(d1a, d1b), fminf(d2a, d2b));
        int tok = n0 + tid;
        code_i[tok] = ii;
        code_f[tok] = (float)ii;
        atomicAdd(cnt + ii, 1);
        if (s2 - bd < MARGIN_) {              // true top-2 gap below guard band
            int p = atomicAdd(rcnt, 1);
            rlist[p] = tok;
        }
    }
}

// -------------------------------------------------------------------
// exact fp32 re-argmin for near-tie tokens; patch code + histogram
__launch_bounds__(256)
__global__ void k_fix(const float* __restrict__ x, const float* __restrict__ Et,
                      const float* __restrict__ e2, const int* __restrict__ rcnt,
                      const int* __restrict__ rlist, int* __restrict__ code_i,
                      float* __restrict__ code_f, int* __restrict__ cnt) {
    __shared__ float4 xs[32];
    __shared__ float rd[256];
    __shared__ int   ri[256];
    int tid = threadIdx.x;
    int nr = *rcnt;
    for (int it = blockIdx.x; it < nr; it += gridDim.x) {
        __syncthreads();
        int tok = rlist[it];
        if (tid < 32) xs[tid] = ((const float4*)(x + (size_t)tok * D_))[tid];
        __syncthreads();
        float bd = INFINITY; int bb = 0;
        for (int c = tid; c < K_; c += 256) {
            const float4* er = (const float4*)(Et + c * D_);
            float dot = 0.f;
            #pragma unroll 8
            for (int j = 0; j < 32; ++j) {
                float4 e = er[j], xx = xs[j];
                dot = fmaf(xx.x, e.x, dot);
                dot = fmaf(xx.y, e.y, dot);
                dot = fmaf(xx.z, e.z, dot);
                dot = fmaf(xx.w, e.w, dot);
            }
            float dist = e2[c] - 2.f * dot;
            if (dist < bd) { bd = dist; bb = c; }   // c ascending per thread
        }
        rd[tid] = bd; ri[tid] = bb;
        __syncthreads();
        for (int off = 128; off > 0; off >>= 1) {
            if (tid < off) {
                float d2 = rd[tid + off]; int i2 = ri[tid + off];
                if (d2 < rd[tid] || (d2 == rd[tid] && i2 < ri[tid])) { rd[tid] = d2; ri[tid] = i2; }
            }
            __syncthreads();
        }
        if (tid == 0) {
            int nb = ri[0], ob = code_i[tok];
            if (nb != ob) {
                code_i[tok] = nb;
                code_f[tok] = (float)nb;
                atomicAdd(cnt + ob, -1);
                atomicAdd(cnt + nb, 1);
            }
        }
    }
}

// -------------------------------------------------------------------
// exclusive scan of code histogram -> base, cursor (256 thr, shfl scan)
__launch_bounds__(256)
__global__ void k_scan(const int* __restrict__ cnt, int* __restrict__ base,
                       int* __restrict__ cursor) {
    int t = threadIdx.x;
    int lane = t & 63, wv = t >> 6;
    int c[4];
    #pragma unroll
    for (int j = 0; j < 4; ++j) c[j] = cnt[4 * t + j];
    int s = c[0] + c[1] + c[2] + c[3];
    int ps = s;
    #pragma unroll
    for (int m = 1; m < 64; m <<= 1) {
        int o = __shfl_up(ps, m);
        if (lane >= m) ps += o;
    }
    __shared__ int wtot[4];
    if (lane == 63) wtot[wv] = ps;
    __syncthreads();
    int woff = 0;
    for (int i = 0; i < 4; ++i) if (i < wv) woff += wtot[i];
    int run = woff + ps - s;      // exclusive prefix for this thread's 4 codes
    #pragma unroll
    for (int j = 0; j < 4; ++j) {
        cursor[4 * t + j] = run;
        run += c[j];
        base[4 * t + j + 1] = run;
    }
    if (t == 0) base[0] = 0;
}

// -------------------------------------------------------------------
// dequant gather + straight-through + diff partial + token-index scatter.
// Grid-stride; per-block ssq partial -> plain store (no same-address RMW).
__launch_bounds__(256)
__global__ void k_gather(const float* __restrict__ x, const float* __restrict__ Et,
                         const int* __restrict__ code_i, float* __restrict__ outq,
                         int* __restrict__ cursor, int* __restrict__ order,
                         float* __restrict__ ssq_part) {
    float loc = 0.f;
    for (int e4 = blockIdx.x * 256 + threadIdx.x; e4 < N_ * 32; e4 += GATHER_BLOCKS * 256) {
        int n = e4 >> 5, q = e4 & 31;
        int c = code_i[n];
        float4 xi = ((const float4*)x)[e4];
        float4 qv = ((const float4*)Et)[c * 32 + q];
        float4 qs;  // straight-through: x + (q - x), matching reference rounding
        qs.x = xi.x + (qv.x - xi.x);
        qs.y = xi.y + (qv.y - xi.y);
        qs.z = xi.z + (qv.z - xi.z);
        qs.w = xi.w + (qv.w - xi.w);
        ((float4*)outq)[e4] = qs;
        float dx = qs.x - xi.x, dy = qs.y - xi.y, dz = qs.z - xi.z, dw = qs.w - xi.w;
        loc += dx * dx + dy * dy + dz * dz + dw * dw;

        if (q == 0) {
            int pos = atomicAdd(cursor + c, 1);
            order[pos] = n;
        }
    }

    // block reduction of squared-diff -> one plain store per block
    #pragma unroll
    for (int off = 32; off > 0; off >>= 1) loc += __shfl_down(loc, off);
    __shared__ float wsum[4];
    if ((threadIdx.x & 63) == 0) wsum[threadIdx.x >> 6] = loc;
    __syncthreads();
    if (threadIdx.x == 0) ssq_part[blockIdx.x] = wsum[0] + wsum[1] + wsum[2] + wsum[3];
}

// -------------------------------------------------------------------
// segment sum via sorted token lists: block (c, s) sums 1/SSPLIT of code c
__launch_bounds__(128)
__global__ void k_segsum(const float* __restrict__ x, const int* __restrict__ order,
                         const int* __restrict__ base, float* __restrict__ part) {
    int c = blockIdx.x, s = blockIdx.y, d = threadIdx.x;
    int b0 = base[c], b1 = base[c + 1];
    int cnt = b1 - b0;
    int i0 = b0 + (cnt * s) / SSPLIT;
    int i1 = b0 + (cnt * (s + 1)) / SSPLIT;
    float a0 = 0.f, a1 = 0.f, a2 = 0.f, a3 = 0.f;
    int i = i0;
    for (; i + 4 <= i1; i += 4) {
        int n0 = order[i], n1 = order[i + 1], n2 = order[i + 2], n3 = order[i + 3];
        a0 += x[(size_t)n0 * D_ + d];
        a1 += x[(size_t)n1 * D_ + d];
        a2 += x[(size_t)n2 * D_ + d];
        a3 += x[(size_t)n3 * D_ + d];
    }
    for (; i < i1; ++i) a0 += x[(size_t)order[i] * D_ + d];
    part[((size_t)s * K_ + c) * D_ + d] = (a0 + a1) + (a2 + a3);
}

// -------------------------------------------------------------------
// fused stats + embed: each block redundantly reduces n; block 0 also
// writes out_ncs + out_diff. Then EMA mean + divide for its 256 elems.
__launch_bounds__(256)
__global__ void k_embed(const float* __restrict__ em, const float* __restrict__ part,
                        const int* __restrict__ cnt, const float* __restrict__ csz,
                        const float* __restrict__ ssq_part, float* __restrict__ out_nmean,
                        float* __restrict__ out_nemb, float* __restrict__ out_ncs,
                        float* __restrict__ out_diff) {
    int tid = threadIdx.x;
    __shared__ float red[256];

    // ---- n = sum_k ncs_k (redundant per block) ----
    float ls = 0.f;
    for (int j = tid; j < K_; j += 256) ls += csz[j] * DECAY_ + OMD_ * (float)cnt[j];
    red[tid] = ls;
    __syncthreads();
    for (int off = 128; off > 0; off >>= 1) {
        if (tid < off) red[tid] += red[tid + off];
        __syncthreads();
    }
    float n = red[0];
    __syncthreads();

    if (blockIdx.x == 0) {
        // out_ncs
        for (int j = tid; j < K_; j += 256)
            out_ncs[j] = csz[j] * DECAY_ + OMD_ * (float)cnt[j];
        // diff
        float sp = 0.f;
        for (int j = tid; j < GATHER_BLOCKS; j += 256) sp += ssq_part[j];
        red[tid] = sp;
        __syncthreads();
        for (int off = 128; off > 0; off >>= 1) {
            if (tid < off) red[tid] += red[tid + off];
            __syncthreads();
        }
        if (tid == 0) *out_diff = VQC_ * red[0] / (float)(N_ * D_);
    }

    int i = blockIdx.x * 256 + tid;           // over D*K, layout [D][K]
    int k = i & (K_ - 1);
    int d = i >> 10;
    float ncs_k = csz[k] * DECAY_ + OMD_ * (float)cnt[k];
    float csk = (ncs_k + EPS_) / (n + (float)K_ * EPS_) * n;
    float es = 0.f;
    #pragma unroll
    for (int s = 0; s < SSPLIT; ++s) es += part[((size_t)s * K_ + k) * D_ + d];
    float nm = em[i] * DECAY_ + OMD_ * es;
    out_nmean[i] = nm;
    out_nemb[i]  = nm / csk;
}

// -------------------------------------------------------------------
extern "C" void kernel_launch(void* const* d_in, const int* in_sizes, int n_in,
                              void* d_out, int out_size, void* d_ws, size_t ws_size,
                              hipStream_t stream) {
    const float* x   = (const float*)d_in[0];   // [16,4096,128]
    const float* E   = (const float*)d_in[1];   // [128,1024]
    const float* csz = (const float*)d_in[2];   // [1024]
    const float* em  = (const float*)d_in[3];   // [128,1024]
    float* out = (float*)d_out;
    float* W   = (float*)d_ws;

    int*   code_i = (int*)(W + WOFF_CODE);
    float* e2     = W + WOFF_E2;
    int*   cnt    = (int*)(W + WOFF_CNT);
    int*   rcnt   = (int*)(W + WOFF_RCNT);
    int*   base   = (int*)(W + WOFF_BASE);
    int*   cursor = (int*)(W + WOFF_CURS);
    int*   order  = (int*)(W + WOFF_ORDER);
    float* Et     = W + WOFF_ET;
    float* part   = W + WOFF_PART;
    int*   rlist  = (int*)(W + WOFF_RLIST);
    float* ssq_part = (float*)(W + WOFF_RLIST);   // reuse: rlist dead after k_fix
    unsigned short* Ef = (unsigned short*)(W + WOFF_EF);

    k_transpose<<<dim3(32, 4), dim3(32, 8), 0, stream>>>(E, Et, cnt);
    k_prep_ef<<<64, 256, 0, stream>>>(Et, Ef, e2);
    k_argmin_mfma<<<N_ / 64, 256, 0, stream>>>(x, Ef, e2, code_i,
                                               out + OOFF_CODE, cnt, rcnt, rlist);
    k_fix<<<256, 256, 0, stream>>>(x, Et, e2, rcnt, rlist, code_i, out + OOFF_CODE, cnt);
    k_scan<<<1, 256, 0, stream>>>(cnt, base, cursor);
    k_gather<<<GATHER_BLOCKS, 256, 0, stream>>>(x, Et, code_i, out + OOFF_Q,
                                                cursor, order, ssq_part);
    k_segsum<<<dim3(K_, SSPLIT), 128, 0, stream>>>(x, order, base, part);
    k_embed<<<(D_ * K_) / 256, 256, 0, stream>>>(em, part, cnt, csz, ssq_part,
                                                 out + OOFF_NMEAN, out + OOFF_NEMB,
                                                 out + OOFF_NCS, out + OOFF_DIFF);
}

// Round 9
// 264.612 us; speedup vs baseline: 1.1187x; 1.1187x over previous
//
#include <hip/hip_runtime.h>
#include <hip/hip_fp16.h>
#include <math.h>

#define D_ 128
#define K_ 1024
#define N_ 65536
#define DECAY_ 0.99f
#define OMD_ 0.01f
#define EPS_ 1e-5f
#define VQC_ 0.25f
#define SSPLIT 4
#define MARGIN_ 0.1f
#define GATHER_BLOCKS 2048

typedef __attribute__((ext_vector_type(8))) _Float16 half8;
typedef __attribute__((ext_vector_type(4))) float f32x4;

// ---- workspace offsets (in 4-byte elements) ----
#define WOFF_CODE  0          // int[65536]
#define WOFF_E2    65536      // float[1024]
#define WOFF_CNT   66560      // int[1024]
#define WOFF_SSQ   67584      // float[1]
#define WOFF_RCNT  67585      // int[1]    (CNT..RCNT zeroed by k_transpose block 0)
#define WOFF_BASE  67648      // int[1025]
#define WOFF_CURS  68736      // int[1024]
#define WOFF_ORDER 69760      // int[65536]
#define WOFF_ET    136320     // float[131072] (K x D), 16B aligned
#define WOFF_PART  267392     // float[SSPLIT * 131072]
#define WOFF_RLIST 791680     // int[65536]; reused as float ssq_part[GATHER_BLOCKS] after k_fix
#define WOFF_EF    857216     // ushort[131072] frag-ordered fp16 of -2E

// ---- output offsets (in floats), reference return order ----
#define OOFF_Q     0          // [16,4096,128]
#define OOFF_DIFF  8388608    // scalar
#define OOFF_CODE  8388609    // [16,4096]
#define OOFF_NEMB  8454145    // [128,1024]
#define OOFF_NCS   8585217    // [1024]
#define OOFF_NMEAN 8586241    // [128,1024]

// -------------------------------------------------------------------
// E [D][K] -> Et [K][D]; block (0,0) also zeroes cnt[1024]+ssq+rcnt
__global__ void k_transpose(const float* __restrict__ E, float* __restrict__ Et,
                            int* __restrict__ cnt) {
    __shared__ float tile[32][33];
    int k0 = blockIdx.x * 32;
    int d0 = blockIdx.y * 32;
    int tx = threadIdx.x;            // 0..31
    if (blockIdx.x == 0 && blockIdx.y == 0) {
        int t = threadIdx.y * 32 + tx;             // 0..255
        for (int i = t; i < 1026; i += 256) cnt[i] = 0;   // cnt[1024], ssq, rcnt
    }
    for (int ty = threadIdx.y; ty < 32; ty += 8)
        tile[ty][tx] = E[(d0 + ty) * K_ + (k0 + tx)];
    __syncthreads();
    for (int ty = threadIdx.y; ty < 32; ty += 8)
        Et[(k0 + ty) * D_ + (d0 + tx)] = tile[tx][ty];
}

// -------------------------------------------------------------------
// Build fragment-ordered fp16 plane of g = -2*E, and e2[k] = sum E^2.
// Layout: index T = ((g16*4 + s)*64 + L); lane L holds code g16*16+(L&15),
// dims s*32 + (L>>4)*8 .. +8  => B-operand frag for mfma 16x16x32.
__global__ void k_prep_ef(const float* __restrict__ Et, unsigned short* __restrict__ Ef,
                          float* __restrict__ e2) {
    __shared__ float e2s[16];
    int tid = threadIdx.x;
    int b = blockIdx.x;                        // 0..63
    int T = b * 256 + tid;
    int L = tid & 63;
    int code = b * 16 + (L & 15);
    int d0 = ((tid >> 6) & 3) * 32 + ((L >> 4) << 3);
    if (tid < 16) e2s[tid] = 0.f;
    __syncthreads();
    const float* src = Et + code * D_ + d0;
    unsigned short h[8];
    float sq = 0.f;
    #pragma unroll
    for (int j = 0; j < 8; ++j) {
        float e = src[j];
        sq = fmaf(e, e, sq);
        h[j] = __half_as_ushort(__float2half(-2.f * e));
    }
    #pragma unroll
    for (int j = 0; j < 8; ++j) Ef[T * 8 + j] = h[j];
    atomicAdd(&e2s[L & 15], sq);
    __syncthreads();
    if (tid < 16) e2[b * 16 + tid] = e2s[tid];
}

// -------------------------------------------------------------------
// MFMA argmin: dist = e2[k] + x.(-2e), fp16 inputs / fp32 accumulate.
// Block = 64 tokens, 4 waves. Wave (mg,ng): m-tiles 2mg..2mg+1 (32 tokens),
// n-half ng (32 of 64 staged codes) => 16 MACs per LDS frag byte.
// fp16 dist-error sigma ~9e-3; exact top-2 guard at MARGIN_ -> k_fix.
__launch_bounds__(256, 4)
__global__ void k_argmin_mfma(const float* __restrict__ x, const unsigned short* __restrict__ Ef,
                              const float* __restrict__ e2,
                              int* __restrict__ code_i, float* __restrict__ code_f,
                              int* __restrict__ cnt, int* __restrict__ rcnt,
                              int* __restrict__ rlist) {
    __shared__ unsigned short Bs[8192];   // 16 KB, one 64-code chunk (fp16)
    __shared__ float e2s[K_];
    int tid = threadIdx.x;
    int w = tid >> 6, L = tid & 63, quad = L >> 4, col = L & 15;
    int mg = w >> 1, ng = w & 1;
    int n0 = blockIdx.x * 64;

    for (int i = tid; i < K_; i += 256) e2s[i] = e2[i];

    // ---- A fragments: 32 tokens/wave (2 m-tiles), fp16 in registers ----
    half8 ah[2][4];
    #pragma unroll
    for (int mt = 0; mt < 2; ++mt) {
        int tok = n0 + (2 * mg + mt) * 16 + col;
        #pragma unroll
        for (int s = 0; s < 4; ++s) {
            const float* p = x + (size_t)tok * D_ + s * 32 + quad * 8;
            float4 u0 = *(const float4*)(p);
            float4 u1 = *(const float4*)(p + 4);
            ah[mt][s][0] = (_Float16)u0.x; ah[mt][s][1] = (_Float16)u0.y;
            ah[mt][s][2] = (_Float16)u0.z; ah[mt][s][3] = (_Float16)u0.w;
            ah[mt][s][4] = (_Float16)u1.x; ah[mt][s][5] = (_Float16)u1.y;
            ah[mt][s][6] = (_Float16)u1.z; ah[mt][s][7] = (_Float16)u1.w;
        }
    }

    float b1[2][4], b2[2][4];
    int   bi[2][4];
    #pragma unroll
    for (int mt = 0; mt < 2; ++mt)
        #pragma unroll
        for (int r = 0; r < 4; ++r) { b1[mt][r] = INFINITY; b2[mt][r] = INFINITY; bi[mt][r] = 0; }

    for (int q = 0; q < 16; ++q) {
        __syncthreads();
        // ---- stage 64-code chunk: flat 16 KB copy ----
        const float4* gh = (const float4*)(Ef + q * 8192);
        #pragma unroll
        for (int i = 0; i < 4; ++i)
            ((float4*)Bs)[i * 256 + tid] = gh[i * 256 + tid];
        __syncthreads();

        // ---- acc init = e2 of this lane's column (this wave's code half) ----
        f32x4 acc[2][2];   // [m-tile][n-sub]
        #pragma unroll
        for (int nn = 0; nn < 2; ++nn) {
            float ev = e2s[q * 64 + (2 * ng + nn) * 16 + col];
            acc[0][nn] = (f32x4){ev, ev, ev, ev};
            acc[1][nn] = (f32x4){ev, ev, ev, ev};
        }

        // ---- 16 MFMA: 4 k-steps x 2 n-subs x 2 m-tiles ----
        #pragma unroll
        for (int s = 0; s < 4; ++s) {
            half8 bh[2];
            #pragma unroll
            for (int nn = 0; nn < 2; ++nn) {
                int off = (((2 * ng + nn) * 4 + s) * 64 + L) * 8;
                bh[nn] = *(const half8*)(Bs + off);
            }
            #pragma unroll
            for (int nn = 0; nn < 2; ++nn) {
                #pragma unroll
                for (int mt = 0; mt < 2; ++mt)
                    acc[mt][nn] = __builtin_amdgcn_mfma_f32_16x16x32_f16(ah[mt][s], bh[nn], acc[mt][nn], 0, 0, 0);
            }
        }

        // ---- fold into running top-2 (ascending code idx => first-min) ----
        #pragma unroll
        for (int nn = 0; nn < 2; ++nn) {
            int ci = q * 64 + (2 * ng + nn) * 16 + col;
            #pragma unroll
            for (int mt = 0; mt < 2; ++mt) {
                #pragma unroll
                for (int r = 0; r < 4; ++r) {
                    float d = acc[mt][nn][r];
                    if (d < b1[mt][r]) {
                        b2[mt][r] = b1[mt][r];
                        b1[mt][r] = d;
                        bi[mt][r] = ci;
                    } else {
                        b2[mt][r] = fminf(b2[mt][r], d);
                    }
                }
            }
        }
    }

    // ---- cross-lane merge over 16 cols, then cross-half merge via LDS ----
    __syncthreads();                        // Bs dead; overlay merge arrays
    float* md1 = (float*)Bs;                // [64 tokens][2 halves]
    float* md2 = md1 + 128;
    int*   mi1 = (int*)(md2 + 128);

    #pragma unroll
    for (int mt = 0; mt < 2; ++mt) {
        #pragma unroll
        for (int r = 0; r < 4; ++r) {
            float bd = b1[mt][r];
            float s2 = b2[mt][r];
            int   ii = bi[mt][r];
            #pragma unroll
            for (int m = 1; m < 16; m <<= 1) {
                float ob  = __shfl_xor(bd, m);
                int   oi  = __shfl_xor(ii, m);
                float os2 = __shfl_xor(s2, m);
                float hi  = fmaxf(bd, ob);
                s2 = fminf(hi, fminf(s2, os2));   // exact combined second-best
                if (ob < bd || (ob == bd && oi < ii)) { bd = ob; ii = oi; }
            }
            if (col == 0) {
                int tl = (2 * mg + mt) * 16 + quad * 4 + r;
                md1[tl * 2 + ng] = bd;
                md2[tl * 2 + ng] = s2;
                mi1[tl * 2 + ng] = ii;
            }
        }
    }
    __syncthreads();
    if (tid < 64) {
        float d1a = md1[tid * 2], d1b = md1[tid * 2 + 1];
        float d2a = md2[tid * 2], d2b = md2[tid * 2 + 1];
        int   ia  = mi1[tid * 2], ib  = mi1[tid * 2 + 1];
        float bd; int ii;
        if (d1b < d1a || (d1b == d1a && ib < ia)) { bd = d1b; ii = ib; }
        else                                      { bd = d1a; ii = ia; }
        float s2 = fminf(fmaxf(d1a, d1b), fminf(d2a, d2b));
        int tok = n0 + tid;
        code_i[tok] = ii;
        code_f[tok] = (float)ii;
        atomicAdd(cnt + ii, 1);
        if (s2 - bd < MARGIN_) {              // true top-2 gap below guard band
            int p = atomicAdd(rcnt, 1);
            rlist[p] = tok;
        }
    }
}

// -------------------------------------------------------------------
// exact fp32 re-argmin for near-tie tokens (coalesced, wave-cooperative):
// one token per block; each half-wave covers one full code row (32 x float4
// contiguous), 5-step shfl reduce; 8 code-slots sweep K in 128 rounds.
__launch_bounds__(256)
__global__ void k_fix(const float* __restrict__ x, const float* __restrict__ Et,
                      const float* __restrict__ e2, const int* __restrict__ rcnt,
                      const int* __restrict__ rlist, int* __restrict__ code_i,
                      float* __restrict__ code_f, int* __restrict__ cnt) {
    __shared__ float4 xs[32];
    __shared__ float sd[8];
    __shared__ int   si[8];
    int tid = threadIdx.x;
    int lane = tid & 63, w = tid >> 6;
    int half = lane >> 5;        // which of the 2 rows this wave covers
    int q32  = lane & 31;        // float4 index within the row
    int slot = w * 2 + half;     // 0..7: codes c ≡ slot (mod 8)
    int nr = *rcnt;
    for (int it = blockIdx.x; it < nr; it += gridDim.x) {
        __syncthreads();         // protect xs/sd/si from previous iteration
        int tok = rlist[it];
        if (tid < 32) xs[tid] = ((const float4*)(x + (size_t)tok * D_))[tid];
        __syncthreads();
        float4 xv = xs[q32];
        float bd = INFINITY; int bb = 0;
        for (int c0 = 0; c0 < K_; c0 += 8) {
            int c = c0 + slot;
            float4 e = ((const float4*)(Et + (size_t)c * D_))[q32];
            float dot = xv.x * e.x + xv.y * e.y + xv.z * e.z + xv.w * e.w;
            dot += __shfl_xor(dot, 1);
            dot += __shfl_xor(dot, 2);
            dot += __shfl_xor(dot, 4);
            dot += __shfl_xor(dot, 8);
            dot += __shfl_xor(dot, 16);
            float dist = e2[c] - 2.f * dot;
            if (dist < bd) { bd = dist; bb = c; }   // c ascending => first-min
        }
        if (q32 == 0) { sd[slot] = bd; si[slot] = bb; }
        __syncthreads();
        if (tid == 0) {
            float fb = sd[0]; int fi = si[0];
            #pragma unroll
            for (int s = 1; s < 8; ++s) {
                if (sd[s] < fb || (sd[s] == fb && si[s] < fi)) { fb = sd[s]; fi = si[s]; }
            }
            int ob = code_i[tok];
            if (fi != ob) {
                code_i[tok] = fi;
                code_f[tok] = (float)fi;
                atomicAdd(cnt + ob, -1);
                atomicAdd(cnt + fi, 1);
            }
        }
    }
}

// -------------------------------------------------------------------
// exclusive scan of code histogram -> base, cursor (256 thr, shfl scan)
__launch_bounds__(256)
__global__ void k_scan(const int* __restrict__ cnt, int* __restrict__ base,
                       int* __restrict__ cursor) {
    int t = threadIdx.x;
    int lane = t & 63, wv = t >> 6;
    int c[4];
    #pragma unroll
    for (int j = 0; j < 4; ++j) c[j] = cnt[4 * t + j];
    int s = c[0] + c[1] + c[2] + c[3];
    int ps = s;
    #pragma unroll
    for (int m = 1; m < 64; m <<= 1) {
        int o = __shfl_up(ps, m);
        if (lane >= m) ps += o;
    }
    __shared__ int wtot[4];
    if (lane == 63) wtot[wv] = ps;
    __syncthreads();
    int woff = 0;
    for (int i = 0; i < 4; ++i) if (i < wv) woff += wtot[i];
    int run = woff + ps - s;      // exclusive prefix for this thread's 4 codes
    #pragma unroll
    for (int j = 0; j < 4; ++j) {
        cursor[4 * t + j] = run;
        run += c[j];
        base[4 * t + j + 1] = run;
    }
    if (t == 0) base[0] = 0;
}

// -------------------------------------------------------------------
// dequant gather + straight-through + diff partial + token-index scatter.
// Grid-stride; per-block ssq partial -> plain store (no same-address RMW).
__launch_bounds__(256)
__global__ void k_gather(const float* __restrict__ x, const float* __restrict__ Et,
                         const int* __restrict__ code_i, float* __restrict__ outq,
                         int* __restrict__ cursor, int* __restrict__ order,
                         float* __restrict__ ssq_part) {
    float loc = 0.f;
    for (int e4 = blockIdx.x * 256 + threadIdx.x; e4 < N_ * 32; e4 += GATHER_BLOCKS * 256) {
        int n = e4 >> 5, q = e4 & 31;
        int c = code_i[n];
        float4 xi = ((const float4*)x)[e4];
        float4 qv = ((const float4*)Et)[c * 32 + q];
        float4 qs;  // straight-through: x + (q - x), matching reference rounding
        qs.x = xi.x + (qv.x - xi.x);
        qs.y = xi.y + (qv.y - xi.y);
        qs.z = xi.z + (qv.z - xi.z);
        qs.w = xi.w + (qv.w - xi.w);
        ((float4*)outq)[e4] = qs;
        float dx = qs.x - xi.x, dy = qs.y - xi.y, dz = qs.z - xi.z, dw = qs.w - xi.w;
        loc += dx * dx + dy * dy + dz * dz + dw * dw;

        if (q == 0) {
            int pos = atomicAdd(cursor + c, 1);
            order[pos] = n;
        }
    }

    // block reduction of squared-diff -> one plain store per block
    #pragma unroll
    for (int off = 32; off > 0; off >>= 1) loc += __shfl_down(loc, off);
    __shared__ float wsum[4];
    if ((threadIdx.x & 63) == 0) wsum[threadIdx.x >> 6] = loc;
    __syncthreads();
    if (threadIdx.x == 0) ssq_part[blockIdx.x] = wsum[0] + wsum[1] + wsum[2] + wsum[3];
}

// -------------------------------------------------------------------
// segment sum via sorted token lists: block (c, s) sums 1/SSPLIT of code c
__launch_bounds__(128)
__global__ void k_segsum(const float* __restrict__ x, const int* __restrict__ order,
                         const int* __restrict__ base, float* __restrict__ part) {
    int c = blockIdx.x, s = blockIdx.y, d = threadIdx.x;
    int b0 = base[c], b1 = base[c + 1];
    int cnt = b1 - b0;
    int i0 = b0 + (cnt * s) / SSPLIT;
    int i1 = b0 + (cnt * (s + 1)) / SSPLIT;
    float a0 = 0.f, a1 = 0.f, a2 = 0.f, a3 = 0.f;
    int i = i0;
    for (; i + 4 <= i1; i += 4) {
        int n0 = order[i], n1 = order[i + 1], n2 = order[i + 2], n3 = order[i + 3];
        a0 += x[(size_t)n0 * D_ + d];
        a1 += x[(size_t)n1 * D_ + d];
        a2 += x[(size_t)n2 * D_ + d];
        a3 += x[(size_t)n3 * D_ + d];
    }
    for (; i < i1; ++i) a0 += x[(size_t)order[i] * D_ + d];
    part[((size_t)s * K_ + c) * D_ + d] = (a0 + a1) + (a2 + a3);
}

// -------------------------------------------------------------------
// fused stats + embed: each block redundantly reduces n; block 0 also
// writes out_ncs + out_diff. Then EMA mean + divide for its 256 elems.
__launch_bounds__(256)
__global__ void k_embed(const float* __restrict__ em, const float* __restrict__ part,
                        const int* __restrict__ cnt, const float* __restrict__ csz,
                        const float* __restrict__ ssq_part, float* __restrict__ out_nmean,
                        float* __restrict__ out_nemb, float* __restrict__ out_ncs,
                        float* __restrict__ out_diff) {
    int tid = threadIdx.x;
    __shared__ float red[256];

    // ---- n = sum_k ncs_k (redundant per block) ----
    float ls = 0.f;
    for (int j = tid; j < K_; j += 256) ls += csz[j] * DECAY_ + OMD_ * (float)cnt[j];
    red[tid] = ls;
    __syncthreads();
    for (int off = 128; off > 0; off >>= 1) {
        if (tid < off) red[tid] += red[tid + off];
        __syncthreads();
    }
    float n = red[0];
    __syncthreads();

    if (blockIdx.x == 0) {
        // out_ncs
        for (int j = tid; j < K_; j += 256)
            out_ncs[j] = csz[j] * DECAY_ + OMD_ * (float)cnt[j];
        // diff
        float sp = 0.f;
        for (int j = tid; j < GATHER_BLOCKS; j += 256) sp += ssq_part[j];
        red[tid] = sp;
        __syncthreads();
        for (int off = 128; off > 0; off >>= 1) {
            if (tid < off) red[tid] += red[tid + off];
            __syncthreads();
        }
        if (tid == 0) *out_diff = VQC_ * red[0] / (float)(N_ * D_);
    }

    int i = blockIdx.x * 256 + tid;           // over D*K, layout [D][K]
    int k = i & (K_ - 1);
    int d = i >> 10;
    float ncs_k = csz[k] * DECAY_ + OMD_ * (float)cnt[k];
    float csk = (ncs_k + EPS_) / (n + (float)K_ * EPS_) * n;
    float es = 0.f;
    #pragma unroll
    for (int s = 0; s < SSPLIT; ++s) es += part[((size_t)s * K_ + k) * D_ + d];
    float nm = em[i] * DECAY_ + OMD_ * es;
    out_nmean[i] = nm;
    out_nemb[i]  = nm / csk;
}

// -------------------------------------------------------------------
extern "C" void kernel_launch(void* const* d_in, const int* in_sizes, int n_in,
                              void* d_out, int out_size, void* d_ws, size_t ws_size,
                              hipStream_t stream) {
    const float* x   = (const float*)d_in[0];   // [16,4096,128]
    const float* E   = (const float*)d_in[1];   // [128,1024]
    const float* csz = (const float*)d_in[2];   // [1024]
    const float* em  = (const float*)d_in[3];   // [128,1024]
    float* out = (float*)d_out;
    float* W   = (float*)d_ws;

    int*   code_i = (int*)(W + WOFF_CODE);
    float* e2     = W + WOFF_E2;
    int*   cnt    = (int*)(W + WOFF_CNT);
    int*   rcnt   = (int*)(W + WOFF_RCNT);
    int*   base   = (int*)(W + WOFF_BASE);
    int*   cursor = (int*)(W + WOFF_CURS);
    int*   order  = (int*)(W + WOFF_ORDER);
    float* Et     = W + WOFF_ET;
    float* part   = W + WOFF_PART;
    int*   rlist  = (int*)(W + WOFF_RLIST);
    float* ssq_part = (float*)(W + WOFF_RLIST);   // reuse: rlist dead after k_fix
    unsigned short* Ef = (unsigned short*)(W + WOFF_EF);

    k_transpose<<<dim3(32, 4), dim3(32, 8), 0, stream>>>(E, Et, cnt);
    k_prep_ef<<<64, 256, 0, stream>>>(Et, Ef, e2);
    k_argmin_mfma<<<N_ / 64, 256, 0, stream>>>(x, Ef, e2, code_i,
                                               out + OOFF_CODE, cnt, rcnt, rlist);
    k_fix<<<1024, 256, 0, stream>>>(x, Et, e2, rcnt, rlist, code_i, out + OOFF_CODE, cnt);
    k_scan<<<1, 256, 0, stream>>>(cnt, base, cursor);
    k_gather<<<GATHER_BLOCKS, 256, 0, stream>>>(x, Et, code_i, out + OOFF_Q,
                                                cursor, order, ssq_part);
    k_segsum<<<dim3(K_, SSPLIT), 128, 0, stream>>>(x, order, base, part);
    k_embed<<<(D_ * K_) / 256, 256, 0, stream>>>(em, part, cnt, csz, ssq_part,
                                                 out + OOFF_NMEAN, out + OOFF_NEMB,
                                                 out + OOFF_NCS, out + OOFF_DIFF);
}